// Round 7
// baseline (166.837 us; speedup 1.0000x reference)
//
#include <hip/hip_runtime.h>
#include <hip/hip_bf16.h>
#include <cmath>

// ---------------------------------------------------------------------------
// Mamba block, fused-pass version.
//   B=2, L=2048, D_MODEL=512, D_INNER=1024, D_STATE=16, D_CONV=4, EPS=1e-8
// Pipeline (8 dispatches):
//   prep_all   : x->bf16, W_in^T->bf16, W_out^T->bf16, W_x[:,0:32]^T->bf16
//   gemm_mfma  : GEMM1 -> xin f32 | resb bf16 (split epilogue)
//   conv_bcdt  : conv+SiLU -> xcb bf16; B,C via MFMA; dt in f32 -> scal
//   rates_par  : log-space parallel rates -> scal cols 32:48, RP
//   scan_states/stitch/scan_out : chunked scan (NC=64), bf16 states
//   gemm_mfma  : GEMM2 -> out
// Workspace (floats, ~52 MB): no aliasing.
// ---------------------------------------------------------------------------

#define L_SEQ 2048
#define NBATCH 2
#define DI 1024
#define NC 64
#define LC 32
#define EPS_F 1e-8f
#define LOG_EPS -18.420680744f

typedef __attribute__((ext_vector_type(8))) __bf16 bf16x8;
typedef __attribute__((ext_vector_type(4))) float f32x4;

__device__ __forceinline__ float silu_f(float v) {
    return v / (1.f + __expf(-v));
}

__device__ __forceinline__ ushort bf16_bits(float v) {
    __hip_bfloat16 h = __float2bfloat16(v);
    return *reinterpret_cast<ushort*>(&h);
}

__device__ __forceinline__ float bf2f(ushort u) {
    union { unsigned u; float f; } c;
    c.u = ((unsigned)u) << 16;
    return c.f;
}

// ---------------- bf16 MFMA GEMM: C = A @ Bt^T + bias ----------------------
// Columns [0, nsplit) -> f32 into Cf; columns [nsplit, N) -> bf16 into Cb.
__global__ __launch_bounds__(256) void gemm_mfma(
    const ushort* __restrict__ A, const ushort* __restrict__ Bt,
    const float* __restrict__ bias, float* __restrict__ Cf,
    ushort* __restrict__ Cb, int M, int N, int K, int nsplit)
{
    __shared__ ushort lA[128 * 64];
    __shared__ ushort lB[128 * 64];
    const int tid = threadIdx.x;
    const int w = tid >> 6, ln = tid & 63;
    const int wr = w >> 1, wc = w & 1;
    const int bm = blockIdx.y * 128, bn = blockIdx.x * 128;
    const int q = ln >> 4, r = ln & 15;
    f32x4 acc[4][4] = {};

    for (int k0 = 0; k0 < K; k0 += 64) {
        #pragma unroll
        for (int j = 0; j < 4; ++j) {
            int c = w * 4 + j;
            int i = c * 64 + ln;
            int m = i >> 3, k8 = (i & 7) * 8;
            __builtin_amdgcn_global_load_lds(
                (const __attribute__((address_space(1))) void*)(A + (size_t)(bm + m) * K + k0 + k8),
                (__attribute__((address_space(3))) void*)(lA + (size_t)i * 8),
                16, 0, 0);
            __builtin_amdgcn_global_load_lds(
                (const __attribute__((address_space(1))) void*)(Bt + (size_t)(bn + m) * K + k0 + k8),
                (__attribute__((address_space(3))) void*)(lB + (size_t)i * 8),
                16, 0, 0);
        }
        __syncthreads();
        #pragma unroll
        for (int kk = 0; kk < 2; ++kk) {
            const int ko = kk * 32 + q * 8;
            bf16x8 af[4], bfr[4];
            #pragma unroll
            for (int m = 0; m < 4; ++m)
                af[m] = *reinterpret_cast<const bf16x8*>(&lA[(wr * 64 + m * 16 + r) * 64 + ko]);
            #pragma unroll
            for (int n = 0; n < 4; ++n)
                bfr[n] = *reinterpret_cast<const bf16x8*>(&lB[(wc * 64 + n * 16 + r) * 64 + ko]);
            #pragma unroll
            for (int m = 0; m < 4; ++m)
                #pragma unroll
                for (int n = 0; n < 4; ++n)
                    acc[m][n] = __builtin_amdgcn_mfma_f32_16x16x32_bf16(af[m], bfr[n], acc[m][n], 0, 0, 0);
        }
        __syncthreads();
    }

    const bool f32path = (bn < nsplit);
    #pragma unroll
    for (int n = 0; n < 4; ++n) {
        int col = bn + wc * 64 + n * 16 + r;
        float bv = bias[col];
        #pragma unroll
        for (int m = 0; m < 4; ++m) {
            int row0 = bm + wr * 64 + m * 16 + q * 4;
            #pragma unroll
            for (int j = 0; j < 4; ++j) {
                float v = acc[m][n][j] + bv;
                if (f32path)
                    Cf[(size_t)(row0 + j) * nsplit + col] = v;
                else
                    Cb[(size_t)(row0 + j) * (N - nsplit) + (col - nsplit)] = bf16_bits(v);
            }
        }
    }
}

// ---------------- prep: all input casts in one launch ----------------------
// bid [0,2048)    : x -> xbf (float4 granules)
// bid [2048,2304) : W_in (512x2048) -> Wt1 (2048x512) transpose-cast
// bid [2304,2432) : W_out (1024x512) -> Wt2 (512x1024) transpose-cast
// bid [2432,2560) : W_x[:,0:32]^T -> Wxt (32x1024)
__global__ __launch_bounds__(256) void prep_all(
    const float* __restrict__ x, const float* __restrict__ W_in,
    const float* __restrict__ W_out, const float* __restrict__ W_x,
    ushort* __restrict__ xbf, ushort* __restrict__ Wt1,
    ushort* __restrict__ Wt2, ushort* __restrict__ Wxt)
{
    const int bid = blockIdx.x;
    const int t = threadIdx.x;
    if (bid < 2048) {
        int i = bid * 256 + t;                       // < 524288 float4s
        float4 v = reinterpret_cast<const float4*>(x)[i];
        ushort4 o;
        o.x = bf16_bits(v.x); o.y = bf16_bits(v.y);
        o.z = bf16_bits(v.z); o.w = bf16_bits(v.w);
        reinterpret_cast<ushort4*>(xbf)[i] = o;
        return;
    }
    if (bid >= 2432) {
        int idx = (bid - 2432) * 256 + t;            // < 32768
        int c = idx >> 10, k = idx & 1023;
        Wxt[idx] = bf16_bits(W_x[(size_t)k * 33 + c]);
        return;
    }
    __shared__ float ld[64][65];
    const float* src; ushort* dst; int R, C, tile;
    if (bid < 2304) { src = W_in;  dst = Wt1; R = 512;  C = 2048; tile = bid - 2048; }
    else            { src = W_out; dst = Wt2; R = 1024; C = 512;  tile = bid - 2304; }
    const int ctiles = C / 64;
    const int r0 = (tile / ctiles) * 64, c0 = (tile % ctiles) * 64;
    #pragma unroll
    for (int i = 0; i < 16; ++i) {
        int idx = t + i * 256;
        int rr = idx >> 6, cc = idx & 63;
        ld[rr][cc] = src[(size_t)(r0 + rr) * C + c0 + cc];
    }
    __syncthreads();
    #pragma unroll
    for (int i = 0; i < 16; ++i) {
        int idx = t + i * 256;
        int cc = idx >> 6, rr = idx & 63;
        dst[(size_t)(c0 + cc) * R + r0 + rr] = bf16_bits(ld[rr][cc]);
    }
}

// ---------------- fused conv+SiLU + BCdt --------------------------------
// Block = 32 rows (one batch; 2048 % 32 == 0), 256 threads, grid 128.
// Per 64-wide d-panel: stage xin (f32) + Wxt + conv params; conv+SiLU in
// f32 regs; dt dot accumulated in f32 (pre-rounding); bf16 tile -> LDS ->
// MFMA vs Wxt for B/C; bf16 tile also streamed to xcb.
__global__ __launch_bounds__(256) void conv_bcdt(
    const float* __restrict__ xin, const float* __restrict__ cw,
    const float* __restrict__ cb, const ushort* __restrict__ Wxt,
    const float* __restrict__ W_x, const float* __restrict__ b_x,
    ushort* __restrict__ xcb, float* __restrict__ scal)
{
    __shared__ float  sxin[35][64];
    __shared__ ushort sxc[32][64];
    __shared__ ushort sw[32][64];
    __shared__ float  swcol[64];
    __shared__ float  scw[64][4];
    __shared__ float  scb[64];
    __shared__ float  sdt[32][8];

    const int t = threadIdx.x;
    const int row0 = blockIdx.x * 32;            // global row (b*L + l0)
    const int l0 = row0 & (L_SEQ - 1);
    const int w = t >> 6, ln = t & 63;
    const int rt = w & 1, ct = w >> 1;
    const int q = ln >> 4, r = ln & 15;
    const int crow = t >> 3, tc = t & 7;

    f32x4 acc = {};
    float dtp = 0.f;

    for (int p = 0; p < 16; ++p) {
        const int d0 = p * 64;
        // stage xin rows [row0-3, row0+32) x [d0, d0+64)
        for (int i = t; i < 35 * 64; i += 256) {
            int rr = i >> 6, cc = i & 63;
            sxin[rr][cc] = (l0 + rr - 3 >= 0)
                ? xin[(size_t)(row0 + rr - 3) * 1024 + d0 + cc] : 0.f;
        }
        // stage Wxt panel 32 x 64
        {
            int c = t >> 3, k8 = (t & 7) * 8;
            *reinterpret_cast<uint4*>(&sw[c][k8]) =
                *reinterpret_cast<const uint4*>(&Wxt[(size_t)c * 1024 + d0 + k8]);
        }
        // stage conv weights/bias + dt weight slice
        scw[t >> 2][t & 3] = cw[(size_t)(d0 + (t >> 2)) * 4 + (t & 3)];
        if (t < 64) { scb[t] = cb[d0 + t]; swcol[t] = W_x[(size_t)(d0 + t) * 33 + 32]; }
        __syncthreads();

        // conv + SiLU for my row x 8 d's; dt partial in f32
        ushort ov[8];
        #pragma unroll
        for (int j = 0; j < 8; ++j) {
            int d = tc * 8 + j;
            float a = scb[d];
            a = fmaf(sxin[crow + 0][d], scw[d][0], a);
            a = fmaf(sxin[crow + 1][d], scw[d][1], a);
            a = fmaf(sxin[crow + 2][d], scw[d][2], a);
            a = fmaf(sxin[crow + 3][d], scw[d][3], a);
            float v = silu_f(a);
            dtp = fmaf(v, swcol[d], dtp);
            ov[j] = bf16_bits(v);
        }
        *reinterpret_cast<uint4*>(&sxc[crow][tc * 8]) = *reinterpret_cast<uint4*>(ov);
        *reinterpret_cast<uint4*>(&xcb[(size_t)(row0 + crow) * 1024 + d0 + tc * 8]) =
            *reinterpret_cast<uint4*>(ov);
        __syncthreads();

        // MFMA: wave (rt, ct): rows rt*16.., cols ct*16..
        #pragma unroll
        for (int kk = 0; kk < 2; ++kk) {
            const int ko = kk * 32 + q * 8;
            bf16x8 af = *reinterpret_cast<const bf16x8*>(&sxc[rt * 16 + r][ko]);
            bf16x8 bf = *reinterpret_cast<const bf16x8*>(&sw[ct * 16 + r][ko]);
            acc = __builtin_amdgcn_mfma_f32_16x16x32_bf16(af, bf, acc, 0, 0, 0);
        }
        __syncthreads();
    }

    // epilogue: B/C columns
    {
        int col = ct * 16 + r;
        float bv = b_x[col];
        #pragma unroll
        for (int j = 0; j < 4; ++j)
            scal[(size_t)(row0 + rt * 16 + q * 4 + j) * 48 + col] = acc[j] + bv;
    }
    // epilogue: dt (f32)
    sdt[crow][tc] = dtp;
    __syncthreads();
    if (t < 32) {
        float s = 0.f;
        #pragma unroll
        for (int j = 0; j < 8; ++j) s += sdt[t][j];
        scal[(size_t)(row0 + t) * 48 + 32] = s + b_x[32];
    }
}

// ---------------- parallel rates via log-space scan (NC=64) ----------------
__global__ __launch_bounds__(256) void rates_par(
    float* __restrict__ scal, const float* __restrict__ A_log,
    float* __restrict__ RP)
{
    int b = blockIdx.x;
    int t = threadIdx.x;
    __shared__ float cdt[L_SEQ];
    __shared__ float wsum[4];
    __shared__ float An[16];
    if (t < 16) An[t] = -__expf(A_log[t]);
    float* base = scal + (long)b * L_SEQ * 48;

    float dt[8];
    float run = 0.f;
    const int l0 = t * 8;
    #pragma unroll
    for (int i = 0; i < 8; ++i) {
        float raw = base[(l0 + i) * 48 + 32];
        float d = (raw > 20.f) ? raw : log1pf(__expf(raw));
        dt[i] = d;
        run += d;
        cdt[l0 + i] = run;
    }

    float x = run;
    int lane = t & 63;
    #pragma unroll
    for (int d = 1; d < 64; d <<= 1) {
        float v = __shfl_up(x, d, 64);
        if (lane >= d) x += v;
    }
    int w = t >> 6;
    if (lane == 63) wsum[w] = x;
    __syncthreads();
    float woff = 0.f;
    for (int i = 0; i < w; ++i) woff += wsum[i];
    float toff = woff + x - run;
    #pragma unroll
    for (int i = 0; i < 8; ++i) cdt[l0 + i] += toff;
    __syncthreads();

    float cprev = (l0 == 0) ? 0.f : cdt[l0 - 1];
    #pragma unroll
    for (int i = 0; i < 8; ++i) {
        int l = l0 + i;
        float cl = cdt[l];
        float rv[16];
        #pragma unroll
        for (int s = 0; s < 16; ++s) {
            float A = An[s];
            float rr;
            if (A * cl >= LOG_EPS) {
                rr = __expf(A * dt[i]);
            } else {
                float lp = A * cprev;
                rr = (lp >= LOG_EPS) ? EPS_F / __expf(lp) : 1.f;
            }
            rv[s] = rr;
        }
        float4* dst = reinterpret_cast<float4*>(base + l * 48 + 32);
        dst[0] = *reinterpret_cast<float4*>(&rv[0]);
        dst[1] = *reinterpret_cast<float4*>(&rv[4]);
        dst[2] = *reinterpret_cast<float4*>(&rv[8]);
        dst[3] = *reinterpret_cast<float4*>(&rv[12]);
        cprev = cl;
    }

    if ((t & 3) == 3) {
        int c = t >> 2;
        float ce = cdt[c * LC + LC - 1];
        float cp = (c == 0) ? 0.f : cdt[c * LC - 1];
        for (int s = 0; s < 16; ++s) {
            float A = An[s];
            float pe = fmaxf(__expf(A * ce), EPS_F);
            float pp = fmaxf(__expf(A * cp), EPS_F);
            RP[(b * NC + c) * 16 + s] = pe / pp;
        }
    }
}

// ---------------- phase A: per-chunk local end states (bf16 in/out) --------
__global__ __launch_bounds__(128) void scan_states(
    const float* __restrict__ scal, const ushort* __restrict__ xcb,
    ushort* __restrict__ Sbf)
{
    int b = blockIdx.z, c = blockIdx.y;
    int d = blockIdx.x * 128 + threadIdx.x;
    __shared__ float sc[LC * 48];
    const float4* src = reinterpret_cast<const float4*>(scal + ((long)(b * L_SEQ) + c * LC) * 48);
    float4* dst = reinterpret_cast<float4*>(sc);
    for (int i = threadIdx.x; i < LC * 48 / 4; i += 128) dst[i] = src[i];

    const ushort* xcp = xcb + ((long)(b * L_SEQ) + c * LC) * 1024 + d;
    float xv[LC];
    #pragma unroll
    for (int ll = 0; ll < LC; ++ll) xv[ll] = bf2f(xcp[(long)ll * 1024]);
    __syncthreads();

    float h[16];
    #pragma unroll
    for (int s = 0; s < 16; ++s) h[s] = 0.f;
    #pragma unroll
    for (int ll = 0; ll < LC; ++ll) {
        const float* e = sc + ll * 48;
        #pragma unroll
        for (int s = 0; s < 16; ++s) h[s] = fmaf(e[32 + s], h[s], e[s] * xv[ll]);
    }
    ushort* Sp = Sbf + ((long)(b * NC + c) * 16) * 1024 + d;
    #pragma unroll
    for (int s = 0; s < 16; ++s) Sp[(long)s * 1024] = bf16_bits(h[s]);
}

// ---------------- stitch (in-place, batched) --------------------------------
__global__ __launch_bounds__(256) void stitch(
    ushort* __restrict__ Sbf, const float* __restrict__ RP)
{
    const int tid = threadIdx.x;
    const int idx = blockIdx.x * 256 + tid;
    const int b = blockIdx.y;
    const int d = idx & 1023, s = idx >> 10;
    __shared__ float rps[NC];
    if (tid < NC) rps[tid] = RP[(b * NC + tid) * 16 + s];

    const long base = ((long)(b * NC) * 16 + s) * 1024 + d;
    const long cs = 16 * 1024;
    float v[NC];
    #pragma unroll
    for (int c = 0; c < NC; ++c) v[c] = bf2f(Sbf[base + c * cs]);
    __syncthreads();
    float H = 0.f;
    #pragma unroll
    for (int c = 0; c < NC; ++c) {
        float tmp = v[c];
        v[c] = H;
        H = fmaf(rps[c], H, tmp);
    }
    #pragma unroll
    for (int c = 0; c < NC; ++c) Sbf[base + c * cs] = bf16_bits(v[c]);
}

// ---------------- phase B: full scan + y + gating -> bf16 ------------------
__global__ __launch_bounds__(128) void scan_out(
    const float* __restrict__ scal, const ushort* __restrict__ xcb,
    const ushort* __restrict__ Hin, const float* __restrict__ Dw,
    const ushort* __restrict__ resb, ushort* __restrict__ ybf)
{
    int b = blockIdx.z, c = blockIdx.y;
    int d = blockIdx.x * 128 + threadIdx.x;
    __shared__ float sc[LC * 48];
    const float4* src = reinterpret_cast<const float4*>(scal + ((long)(b * L_SEQ) + c * LC) * 48);
    float4* dst = reinterpret_cast<float4*>(sc);
    for (int i = threadIdx.x; i < LC * 48 / 4; i += 128) dst[i] = src[i];

    const long row0 = (long)(b * L_SEQ) + c * LC;
    float xv[LC], rv[LC];
    #pragma unroll
    for (int ll = 0; ll < LC; ++ll) xv[ll] = bf2f(xcb[(row0 + ll) * 1024 + d]);
    #pragma unroll
    for (int ll = 0; ll < LC; ++ll) rv[ll] = bf2f(resb[(row0 + ll) * 1024 + d]);
    float h[16];
    long hoff = ((long)(b * NC + c) * 16) * 1024 + d;
    #pragma unroll
    for (int s = 0; s < 16; ++s) h[s] = bf2f(Hin[hoff + (long)s * 1024]);
    __syncthreads();

    float Dd = Dw[d];
    #pragma unroll
    for (int ll = 0; ll < LC; ++ll) {
        const float* e = sc + ll * 48;
        float y = 0.f;
        #pragma unroll
        for (int s = 0; s < 16; ++s) {
            h[s] = fmaf(e[32 + s], h[s], e[s] * xv[ll]);
            y = fmaf(e[16 + s], h[s], y);
        }
        y = fmaf(Dd, xv[ll], y);
        ybf[(row0 + ll) * 1024 + d] = bf16_bits(y * silu_f(rv[ll]));
    }
}

// ---------------------------------------------------------------------------
extern "C" void kernel_launch(void* const* d_in, const int* in_sizes, int n_in,
                              void* d_out, int out_size, void* d_ws, size_t ws_size,
                              hipStream_t stream)
{
    const float* x      = (const float*)d_in[0];
    const float* W_in   = (const float*)d_in[1];
    const float* b_in   = (const float*)d_in[2];
    const float* conv_w = (const float*)d_in[3];
    const float* conv_b = (const float*)d_in[4];
    const float* W_x    = (const float*)d_in[5];
    const float* b_x    = (const float*)d_in[6];
    const float* A_log  = (const float*)d_in[7];
    const float* Dw     = (const float*)d_in[8];
    const float* W_out  = (const float*)d_in[9];
    const float* b_out  = (const float*)d_in[10];
    float* out = (float*)d_out;

    float* ws    = (float*)d_ws;
    float* xin   = ws;                          // 4,194,304 f
    ushort* resb = (ushort*)(xin + 4194304);    // 4,194,304 u
    ushort* xcb  = resb + 4194304;              // 4,194,304 u
    float* scal  = (float*)(xcb + 4194304);     //   196,608 f
    ushort* Sbf  = (ushort*)(scal + 196608);    // 2,097,152 u
    float* RP    = (float*)(Sbf + 2097152);     //     2,048 f
    ushort* xbf  = (ushort*)(RP + 2048);        // 2,097,152 u
    ushort* Wt1  = xbf + 2097152;               // 1,048,576 u
    ushort* Wt2  = Wt1 + 1048576;               //   524,288 u
    ushort* Wxt  = Wt2 + 524288;                //    32,768 u
    ushort* ybf  = Wxt + 32768;                 // 4,194,304 u

    // 0. all input casts (one launch)
    prep_all<<<2560, 256, 0, stream>>>(x, W_in, W_out, W_x, xbf, Wt1, Wt2, Wxt);

    // 1. [xin | resb] = x @ W_in + b_in  (split epilogue: f32 | bf16)
    gemm_mfma<<<dim3(2048 / 128, 4096 / 128), 256, 0, stream>>>(
        xbf, Wt1, b_in, xin, resb, 4096, 2048, 512, 1024);

    // 2. fused conv+SiLU -> xcb; B,C (MFMA) + dt (f32) -> scal
    conv_bcdt<<<4096 / 32, 256, 0, stream>>>(
        xin, conv_w, conv_b, Wxt, W_x, b_x, xcb, scal);

    // 3. parallel log-space rates
    rates_par<<<NBATCH, 256, 0, stream>>>(scal, A_log, RP);

    // 4-6. fine-chunked scan
    scan_states<<<dim3(DI / 128, NC, NBATCH), 128, 0, stream>>>(scal, xcb, Sbf);
    stitch<<<dim3(64, NBATCH), 256, 0, stream>>>(Sbf, RP);
    scan_out<<<dim3(DI / 128, NC, NBATCH), 128, 0, stream>>>(scal, xcb, Sbf, Dw, resb, ybf);

    // 7. out = y_act @ W_out + b_out
    gemm_mfma<<<dim3(512 / 128, 4096 / 128), 256, 0, stream>>>(
        ybf, Wt2, b_out, out, nullptr, 4096, 512, 1024, 512);
}

// Round 8
// 116.127 us; speedup vs baseline: 1.4367x; 1.4367x over previous
//
#include <hip/hip_runtime.h>
#include <hip/hip_bf16.h>
#include <cmath>

// ---------------------------------------------------------------------------
// Mamba block, round 8: r6 structure restored + all-bf16 GEMM1 out,
// dt folded into GEMM3 (48-col), GEMM2 retiled to 128x64 (256 blocks).
//   B=2, L=2048, D_MODEL=512, D_INNER=1024, D_STATE=16, D_CONV=4, EPS=1e-8
// Pipeline (10 dispatches):
//   prep_all -> gemm1 -> conv_silu -> gemm3(48) -> reduce -> rates
//   -> scan_states -> stitch -> scan_out -> gemm2
// Workspace ~49 MB, no aliasing.
// ---------------------------------------------------------------------------

#define L_SEQ 2048
#define NBATCH 2
#define DI 1024
#define NC 64
#define LC 32
#define EPS_F 1e-8f
#define LOG_EPS -18.420680744f

typedef __attribute__((ext_vector_type(8))) __bf16 bf16x8;
typedef __attribute__((ext_vector_type(4))) float f32x4;

__device__ __forceinline__ float silu_f(float v) {
    return v / (1.f + __expf(-v));
}

__device__ __forceinline__ ushort bf16_bits(float v) {
    __hip_bfloat16 h = __float2bfloat16(v);
    return *reinterpret_cast<ushort*>(&h);
}

__device__ __forceinline__ float bf2f(ushort u) {
    union { unsigned u; float f; } c;
    c.u = ((unsigned)u) << 16;
    return c.f;
}

// ---------------- GEMM1: [xinb | resb] = x @ W_in^T + b (bf16 out) ---------
// 128x128 tile, BK=64, 4 waves 2x2. A: xbf 4096x512, Bt: Wt1 2048x512.
__global__ __launch_bounds__(256) void gemm1_mfma(
    const ushort* __restrict__ A, const ushort* __restrict__ Bt,
    const float* __restrict__ bias, ushort* __restrict__ C0,
    ushort* __restrict__ C1, int M, int N, int K)
{
    __shared__ ushort lA[128 * 64];
    __shared__ ushort lB[128 * 64];
    const int tid = threadIdx.x;
    const int w = tid >> 6, ln = tid & 63;
    const int wr = w >> 1, wc = w & 1;
    const int bm = blockIdx.y * 128, bn = blockIdx.x * 128;
    const int q = ln >> 4, r = ln & 15;
    f32x4 acc[4][4] = {};

    for (int k0 = 0; k0 < K; k0 += 64) {
        #pragma unroll
        for (int j = 0; j < 4; ++j) {
            int i = (w * 4 + j) * 64 + ln;
            int m = i >> 3, k8 = (i & 7) * 8;
            __builtin_amdgcn_global_load_lds(
                (const __attribute__((address_space(1))) void*)(A + (size_t)(bm + m) * K + k0 + k8),
                (__attribute__((address_space(3))) void*)(lA + (size_t)i * 8),
                16, 0, 0);
            __builtin_amdgcn_global_load_lds(
                (const __attribute__((address_space(1))) void*)(Bt + (size_t)(bn + m) * K + k0 + k8),
                (__attribute__((address_space(3))) void*)(lB + (size_t)i * 8),
                16, 0, 0);
        }
        __syncthreads();
        #pragma unroll
        for (int kk = 0; kk < 2; ++kk) {
            const int ko = kk * 32 + q * 8;
            bf16x8 af[4], bfr[4];
            #pragma unroll
            for (int m = 0; m < 4; ++m)
                af[m] = *reinterpret_cast<const bf16x8*>(&lA[(wr * 64 + m * 16 + r) * 64 + ko]);
            #pragma unroll
            for (int n = 0; n < 4; ++n)
                bfr[n] = *reinterpret_cast<const bf16x8*>(&lB[(wc * 64 + n * 16 + r) * 64 + ko]);
            #pragma unroll
            for (int m = 0; m < 4; ++m)
                #pragma unroll
                for (int n = 0; n < 4; ++n)
                    acc[m][n] = __builtin_amdgcn_mfma_f32_16x16x32_bf16(af[m], bfr[n], acc[m][n], 0, 0, 0);
        }
        __syncthreads();
    }

    const bool lo = (bn < 1024);                 // nsplit=1024, tile-uniform
    #pragma unroll
    for (int n = 0; n < 4; ++n) {
        int col = bn + wc * 64 + n * 16 + r;
        float bv = bias[col];
        #pragma unroll
        for (int m = 0; m < 4; ++m) {
            int row0 = bm + wr * 64 + m * 16 + q * 4;
            #pragma unroll
            for (int j = 0; j < 4; ++j) {
                ushort v = bf16_bits(acc[m][n][j] + bv);
                if (lo) C0[(size_t)(row0 + j) * 1024 + col];
                if (lo) C0[(size_t)(row0 + j) * 1024 + col] = v;
                else    C1[(size_t)(row0 + j) * 1024 + (col - 1024)] = v;
            }
        }
    }
}

// ---------------- GEMM2: out = ybf @ Wt2^T + b (f32 out, 128x64 tile) ------
__global__ __launch_bounds__(256) void gemm2_mfma(
    const ushort* __restrict__ A, const ushort* __restrict__ Bt,
    const float* __restrict__ bias, float* __restrict__ C,
    int M, int N, int K)
{
    __shared__ ushort lA[128 * 64];
    __shared__ ushort lB[64 * 64];
    const int tid = threadIdx.x;
    const int w = tid >> 6, ln = tid & 63;
    const int wr = w >> 1, wc = w & 1;
    const int bm = blockIdx.y * 128, bn = blockIdx.x * 64;
    const int q = ln >> 4, r = ln & 15;
    f32x4 acc[4][2] = {};

    for (int k0 = 0; k0 < K; k0 += 64) {
        #pragma unroll
        for (int j = 0; j < 4; ++j) {
            int i = (w * 4 + j) * 64 + ln;
            int m = i >> 3, k8 = (i & 7) * 8;
            __builtin_amdgcn_global_load_lds(
                (const __attribute__((address_space(1))) void*)(A + (size_t)(bm + m) * K + k0 + k8),
                (__attribute__((address_space(3))) void*)(lA + (size_t)i * 8),
                16, 0, 0);
        }
        #pragma unroll
        for (int j = 0; j < 2; ++j) {
            int i = (w * 2 + j) * 64 + ln;
            int m = i >> 3, k8 = (i & 7) * 8;
            __builtin_amdgcn_global_load_lds(
                (const __attribute__((address_space(1))) void*)(Bt + (size_t)(bn + m) * K + k0 + k8),
                (__attribute__((address_space(3))) void*)(lB + (size_t)i * 8),
                16, 0, 0);
        }
        __syncthreads();
        #pragma unroll
        for (int kk = 0; kk < 2; ++kk) {
            const int ko = kk * 32 + q * 8;
            bf16x8 af[4], bfr[2];
            #pragma unroll
            for (int m = 0; m < 4; ++m)
                af[m] = *reinterpret_cast<const bf16x8*>(&lA[(wr * 64 + m * 16 + r) * 64 + ko]);
            #pragma unroll
            for (int n = 0; n < 2; ++n)
                bfr[n] = *reinterpret_cast<const bf16x8*>(&lB[(wc * 32 + n * 16 + r) * 64 + ko]);
            #pragma unroll
            for (int m = 0; m < 4; ++m)
                #pragma unroll
                for (int n = 0; n < 2; ++n)
                    acc[m][n] = __builtin_amdgcn_mfma_f32_16x16x32_bf16(af[m], bfr[n], acc[m][n], 0, 0, 0);
        }
        __syncthreads();
    }

    #pragma unroll
    for (int n = 0; n < 2; ++n) {
        int col = bn + wc * 32 + n * 16 + r;
        float bv = bias[col];
        #pragma unroll
        for (int m = 0; m < 4; ++m) {
            int row0 = bm + wr * 64 + m * 16 + q * 4;
            #pragma unroll
            for (int j = 0; j < 4; ++j)
                C[(size_t)(row0 + j) * N + col] = acc[m][n][j] + bv;
        }
    }
}

// ---------------- GEMM3 partials: P[ks][4096][48] = xcb @ Wxt^T ------------
// Wxt is 48x1024 (rows 0-31: B/C weights, 32: dt col, 33-47: zero).
__global__ __launch_bounds__(256) void gemm3_mfma(
    const ushort* __restrict__ A, const ushort* __restrict__ Bt,
    float* __restrict__ P)
{
    __shared__ ushort lA[64 * 64];
    __shared__ ushort lB[48 * 64];
    const int t = threadIdx.x;
    const int w = t >> 6, ln = t & 63;
    const int q = ln >> 4, r = ln & 15;
    const int bm = blockIdx.y * 64;
    const int ks = blockIdx.x;
    f32x4 acc[3] = {};

    for (int k0 = ks * 256; k0 < ks * 256 + 256; k0 += 64) {
        #pragma unroll
        for (int j = 0; j < 2; ++j) {
            int i = (w * 2 + j) * 64 + ln;
            int m = i >> 3, k8 = (i & 7) * 8;
            __builtin_amdgcn_global_load_lds(
                (const __attribute__((address_space(1))) void*)(A + (size_t)(bm + m) * 1024 + k0 + k8),
                (__attribute__((address_space(3))) void*)(lA + (size_t)i * 8),
                16, 0, 0);
        }
        #pragma unroll
        for (int p = 0; p < 2; ++p) {
            int cidx = p * 4 + w;
            if (cidx < 6) {                       // wave-uniform predicate
                int i = cidx * 64 + ln;
                int m = i >> 3, k8 = (i & 7) * 8;
                __builtin_amdgcn_global_load_lds(
                    (const __attribute__((address_space(1))) void*)(Bt + (size_t)m * 1024 + k0 + k8),
                    (__attribute__((address_space(3))) void*)(lB + (size_t)i * 8),
                    16, 0, 0);
            }
        }
        __syncthreads();
        #pragma unroll
        for (int kk = 0; kk < 2; ++kk) {
            const int ko = kk * 32 + q * 8;
            bf16x8 af = *reinterpret_cast<const bf16x8*>(&lA[(w * 16 + r) * 64 + ko]);
            #pragma unroll
            for (int n = 0; n < 3; ++n) {
                bf16x8 bf = *reinterpret_cast<const bf16x8*>(&lB[(n * 16 + r) * 64 + ko]);
                acc[n] = __builtin_amdgcn_mfma_f32_16x16x32_bf16(af, bf, acc[n], 0, 0, 0);
            }
        }
        __syncthreads();
    }

    const int row0 = bm + w * 16 + q * 4;
    const size_t base = (size_t)ks * 196608;
    #pragma unroll
    for (int n = 0; n < 3; ++n)
        #pragma unroll
        for (int j = 0; j < 4; ++j)
            P[base + (size_t)(row0 + j) * 48 + n * 16 + r] = acc[n][j];
}

// ---------------- GEMM3 reduce: scal[l][c] = b_x[c] + sum_ks P (c<33) ------
__global__ __launch_bounds__(256) void gemm3_reduce(
    const float* __restrict__ P, const float* __restrict__ b_x,
    float* __restrict__ scal)
{
    int idx = blockIdx.x * 256 + threadIdx.x;     // < 196608
    int l = idx / 48, c = idx - l * 48;
    if (c >= 33) return;
    float v = b_x[c] + P[idx] + P[idx + 196608] + P[idx + 393216] + P[idx + 589824];
    scal[(size_t)l * 48 + c] = v;
}

// ---------------- prep: all input casts in one launch ----------------------
// bid [0,2048)    : x -> xbf
// bid [2048,2304) : W_in (512x2048) -> Wt1 (2048x512)
// bid [2304,2432) : W_out (1024x512) -> Wt2 (512x1024)
// bid [2432,2624) : W_x -> Wxt (48x1024; rows>32 zero)
__global__ __launch_bounds__(256) void prep_all(
    const float* __restrict__ x, const float* __restrict__ W_in,
    const float* __restrict__ W_out, const float* __restrict__ W_x,
    ushort* __restrict__ xbf, ushort* __restrict__ Wt1,
    ushort* __restrict__ Wt2, ushort* __restrict__ Wxt)
{
    const int bid = blockIdx.x;
    const int t = threadIdx.x;
    if (bid < 2048) {
        int i = bid * 256 + t;
        float4 v = reinterpret_cast<const float4*>(x)[i];
        ushort4 o;
        o.x = bf16_bits(v.x); o.y = bf16_bits(v.y);
        o.z = bf16_bits(v.z); o.w = bf16_bits(v.w);
        reinterpret_cast<ushort4*>(xbf)[i] = o;
        return;
    }
    if (bid >= 2432) {
        int idx = (bid - 2432) * 256 + t;            // < 49152
        int c = idx >> 10, k = idx & 1023;
        Wxt[idx] = (c < 33) ? bf16_bits(W_x[(size_t)k * 33 + c]) : (ushort)0;
        return;
    }
    __shared__ float ld[64][65];
    const float* src; ushort* dst; int R, C, tile;
    if (bid < 2304) { src = W_in;  dst = Wt1; R = 512;  C = 2048; tile = bid - 2048; }
    else            { src = W_out; dst = Wt2; R = 1024; C = 512;  tile = bid - 2304; }
    const int ctiles = C / 64;
    const int r0 = (tile / ctiles) * 64, c0 = (tile % ctiles) * 64;
    #pragma unroll
    for (int i = 0; i < 16; ++i) {
        int idx = t + i * 256;
        int rr = idx >> 6, cc = idx & 63;
        ld[rr][cc] = src[(size_t)(r0 + rr) * C + c0 + cc];
    }
    __syncthreads();
    #pragma unroll
    for (int i = 0; i < 16; ++i) {
        int idx = t + i * 256;
        int cc = idx >> 6, rr = idx & 63;
        dst[(size_t)(c0 + cc) * R + r0 + rr] = bf16_bits(ld[rr][cc]);
    }
}

// ---------------- depthwise causal conv(4) + SiLU (bf16 in/out) ------------
__global__ __launch_bounds__(256) void conv_silu(
    const ushort* __restrict__ xinb, const float* __restrict__ cw,
    const float* __restrict__ cb, ushort* __restrict__ xcb)
{
    int idx = blockIdx.x * 256 + threadIdx.x;
    int d = idx & (DI - 1);
    int l = (idx >> 10) & (L_SEQ - 1);
    float4 w = *reinterpret_cast<const float4*>(cw + d * 4);
    float acc = cb[d];
    long base = (long)idx;
    if (l >= 3) acc = fmaf(bf2f(xinb[base - 3 * 1024]), w.x, acc);
    if (l >= 2) acc = fmaf(bf2f(xinb[base - 2 * 1024]), w.y, acc);
    if (l >= 1) acc = fmaf(bf2f(xinb[base - 1 * 1024]), w.z, acc);
    acc = fmaf(bf2f(xinb[base]), w.w, acc);
    xcb[idx] = bf16_bits(silu_f(acc));
}

// ---------------- parallel rates via log-space scan (NC=64) ----------------
__global__ __launch_bounds__(256) void rates_par(
    float* __restrict__ scal, const float* __restrict__ A_log,
    float* __restrict__ RP)
{
    int b = blockIdx.x;
    int t = threadIdx.x;
    __shared__ float cdt[L_SEQ];
    __shared__ float wsum[4];
    __shared__ float An[16];
    if (t < 16) An[t] = -__expf(A_log[t]);
    float* base = scal + (long)b * L_SEQ * 48;

    float dt[8];
    float run = 0.f;
    const int l0 = t * 8;
    #pragma unroll
    for (int i = 0; i < 8; ++i) {
        float raw = base[(l0 + i) * 48 + 32];
        float d = (raw > 20.f) ? raw : log1pf(__expf(raw));
        dt[i] = d;
        run += d;
        cdt[l0 + i] = run;
    }

    float x = run;
    int lane = t & 63;
    #pragma unroll
    for (int d = 1; d < 64; d <<= 1) {
        float v = __shfl_up(x, d, 64);
        if (lane >= d) x += v;
    }
    int w = t >> 6;
    if (lane == 63) wsum[w] = x;
    __syncthreads();
    float woff = 0.f;
    for (int i = 0; i < w; ++i) woff += wsum[i];
    float toff = woff + x - run;
    #pragma unroll
    for (int i = 0; i < 8; ++i) cdt[l0 + i] += toff;
    __syncthreads();

    float cprev = (l0 == 0) ? 0.f : cdt[l0 - 1];
    #pragma unroll
    for (int i = 0; i < 8; ++i) {
        int l = l0 + i;
        float cl = cdt[l];
        float rv[16];
        #pragma unroll
        for (int s = 0; s < 16; ++s) {
            float A = An[s];
            float rr;
            if (A * cl >= LOG_EPS) {
                rr = __expf(A * dt[i]);
            } else {
                float lp = A * cprev;
                rr = (lp >= LOG_EPS) ? EPS_F / __expf(lp) : 1.f;
            }
            rv[s] = rr;
        }
        float4* dst = reinterpret_cast<float4*>(base + l * 48 + 32);
        dst[0] = *reinterpret_cast<float4*>(&rv[0]);
        dst[1] = *reinterpret_cast<float4*>(&rv[4]);
        dst[2] = *reinterpret_cast<float4*>(&rv[8]);
        dst[3] = *reinterpret_cast<float4*>(&rv[12]);
        cprev = cl;
    }

    if ((t & 3) == 3) {
        int c = t >> 2;
        float ce = cdt[c * LC + LC - 1];
        float cp = (c == 0) ? 0.f : cdt[c * LC - 1];
        for (int s = 0; s < 16; ++s) {
            float A = An[s];
            float pe = fmaxf(__expf(A * ce), EPS_F);
            float pp = fmaxf(__expf(A * cp), EPS_F);
            RP[(b * NC + c) * 16 + s] = pe / pp;
        }
    }
}

// ---------------- phase A: per-chunk local end states (bf16 in/out) --------
__global__ __launch_bounds__(128) void scan_states(
    const float* __restrict__ scal, const ushort* __restrict__ xcb,
    ushort* __restrict__ Sbf)
{
    int b = blockIdx.z, c = blockIdx.y;
    int d = blockIdx.x * 128 + threadIdx.x;
    __shared__ float sc[LC * 48];
    const float4* src = reinterpret_cast<const float4*>(scal + ((long)(b * L_SEQ) + c * LC) * 48);
    float4* dst = reinterpret_cast<float4*>(sc);
    for (int i = threadIdx.x; i < LC * 48 / 4; i += 128) dst[i] = src[i];

    const ushort* xcp = xcb + ((long)(b * L_SEQ) + c * LC) * 1024 + d;
    float xv[LC];
    #pragma unroll
    for (int ll = 0; ll < LC; ++ll) xv[ll] = bf2f(xcp[(long)ll * 1024]);
    __syncthreads();

    float h[16];
    #pragma unroll
    for (int s = 0; s < 16; ++s) h[s] = 0.f;
    #pragma unroll
    for (int ll = 0; ll < LC; ++ll) {
        const float* e = sc + ll * 48;
        #pragma unroll
        for (int s = 0; s < 16; ++s) h[s] = fmaf(e[32 + s], h[s], e[s] * xv[ll]);
    }
    ushort* Sp = Sbf + ((long)(b * NC + c) * 16) * 1024 + d;
    #pragma unroll
    for (int s = 0; s < 16; ++s) Sp[(long)s * 1024] = bf16_bits(h[s]);
}

// ---------------- stitch (in-place, batched) --------------------------------
__global__ __launch_bounds__(256) void stitch(
    ushort* __restrict__ Sbf, const float* __restrict__ RP)
{
    const int tid = threadIdx.x;
    const int idx = blockIdx.x * 256 + tid;
    const int b = blockIdx.y;
    const int d = idx & 1023, s = idx >> 10;
    __shared__ float rps[NC];
    if (tid < NC) rps[tid] = RP[(b * NC + tid) * 16 + s];

    const long base = ((long)(b * NC) * 16 + s) * 1024 + d;
    const long cs = 16 * 1024;
    float v[NC];
    #pragma unroll
    for (int c = 0; c < NC; ++c) v[c] = bf2f(Sbf[base + c * cs]);
    __syncthreads();
    float H = 0.f;
    #pragma unroll
    for (int c = 0; c < NC; ++c) {
        float tmp = v[c];
        v[c] = H;
        H = fmaf(rps[c], H, tmp);
    }
    #pragma unroll
    for (int c = 0; c < NC; ++c) Sbf[base + c * cs] = bf16_bits(v[c]);
}

// ---------------- phase B: full scan + y + gating -> bf16 ------------------
__global__ __launch_bounds__(128) void scan_out(
    const float* __restrict__ scal, const ushort* __restrict__ xcb,
    const ushort* __restrict__ Hin, const float* __restrict__ Dw,
    const ushort* __restrict__ resb, ushort* __restrict__ ybf)
{
    int b = blockIdx.z, c = blockIdx.y;
    int d = blockIdx.x * 128 + threadIdx.x;
    __shared__ float sc[LC * 48];
    const float4* src = reinterpret_cast<const float4*>(scal + ((long)(b * L_SEQ) + c * LC) * 48);
    float4* dst = reinterpret_cast<float4*>(sc);
    for (int i = threadIdx.x; i < LC * 48 / 4; i += 128) dst[i] = src[i];

    const long row0 = (long)(b * L_SEQ) + c * LC;
    float xv[LC], rv[LC];
    #pragma unroll
    for (int ll = 0; ll < LC; ++ll) xv[ll] = bf2f(xcb[(row0 + ll) * 1024 + d]);
    #pragma unroll
    for (int ll = 0; ll < LC; ++ll) rv[ll] = bf2f(resb[(row0 + ll) * 1024 + d]);
    float h[16];
    long hoff = ((long)(b * NC + c) * 16) * 1024 + d;
    #pragma unroll
    for (int s = 0; s < 16; ++s) h[s] = bf2f(Hin[hoff + (long)s * 1024]);
    __syncthreads();

    float Dd = Dw[d];
    #pragma unroll
    for (int ll = 0; ll < LC; ++ll) {
        const float* e = sc + ll * 48;
        float y = 0.f;
        #pragma unroll
        for (int s = 0; s < 16; ++s) {
            h[s] = fmaf(e[32 + s], h[s], e[s] * xv[ll]);
            y = fmaf(e[16 + s], h[s], y);
        }
        y = fmaf(Dd, xv[ll], y);
        ybf[(row0 + ll) * 1024 + d] = bf16_bits(y * silu_f(rv[ll]));
    }
}

// ---------------------------------------------------------------------------
extern "C" void kernel_launch(void* const* d_in, const int* in_sizes, int n_in,
                              void* d_out, int out_size, void* d_ws, size_t ws_size,
                              hipStream_t stream)
{
    const float* x      = (const float*)d_in[0];
    const float* W_in   = (const float*)d_in[1];
    const float* b_in   = (const float*)d_in[2];
    const float* conv_w = (const float*)d_in[3];
    const float* conv_b = (const float*)d_in[4];
    const float* W_x    = (const float*)d_in[5];
    const float* b_x    = (const float*)d_in[6];
    const float* A_log  = (const float*)d_in[7];
    const float* Dw     = (const float*)d_in[8];
    const float* W_out  = (const float*)d_in[9];
    const float* b_out  = (const float*)d_in[10];
    float* out = (float*)d_out;

    ushort* u    = (ushort*)d_ws;
    ushort* xinb = u;                           // 4,194,304 u
    ushort* resb = xinb + 4194304;              // 4,194,304 u
    ushort* xcb  = resb + 4194304;              // 4,194,304 u
    ushort* Sbf  = xcb + 4194304;               // 2,097,152 u
    ushort* xbf  = Sbf + 2097152;               // 2,097,152 u
    ushort* Wt1  = xbf + 2097152;               // 1,048,576 u
    ushort* Wt2  = Wt1 + 1048576;               //   524,288 u
    ushort* Wxt  = Wt2 + 524288;                //    49,152 u
    ushort* ybf  = Wxt + 49152;                 // 4,194,304 u
    float* scal  = (float*)(ybf + 4194304);     //   196,608 f
    float* RP    = scal + 196608;               //     2,048 f
    float* P     = RP + 2048;                   //   786,432 f

    // 0. all input casts
    prep_all<<<2624, 256, 0, stream>>>(x, W_in, W_out, W_x, xbf, Wt1, Wt2, Wxt);

    // 1. [xinb | resb] = x @ W_in + b_in  (bf16 epilogue)
    gemm1_mfma<<<dim3(2048 / 128, 4096 / 128), 256, 0, stream>>>(
        xbf, Wt1, b_in, xinb, resb, 4096, 2048, 512);

    // 2. xcb = bf16(silu(conv(xinb)))
    conv_silu<<<(NBATCH * L_SEQ * DI) / 256, 256, 0, stream>>>(xinb, conv_w, conv_b, xcb);

    // 3. GEMM3 (B,C,dt in one 48-col MFMA K-split) + reduce
    gemm3_mfma<<<dim3(4, 4096 / 64), 256, 0, stream>>>(xcb, Wxt, P);
    gemm3_reduce<<<196608 / 256, 256, 0, stream>>>(P, b_x, scal);

    // 4. parallel log-space rates
    rates_par<<<NBATCH, 256, 0, stream>>>(scal, A_log, RP);

    // 5-7. fine-chunked scan
    scan_states<<<dim3(DI / 128, NC, NBATCH), 128, 0, stream>>>(scal, xcb, Sbf);
    stitch<<<dim3(64, NBATCH), 256, 0, stream>>>(Sbf, RP);
    scan_out<<<dim3(DI / 128, NC, NBATCH), 128, 0, stream>>>(scal, xcb, Sbf, Dw, resb, ybf);

    // 8. out = y_act @ W_out + b_out  (128x64 tile, 256 blocks)
    gemm2_mfma<<<dim3(512 / 64, 4096 / 128), 256, 0, stream>>>(
        ybf, Wt2, b_out, out, 4096, 512, 1024);
}